// Round 6
// baseline (812.517 us; speedup 1.0000x reference)
//
#include <hip/hip_runtime.h>
#include <math.h>

#define T_STEPS 2048
#define BATCH   16
#define DIM     1024
#define NSTATE  64
#define NFIELD  256                      // per (t,b): [k_norm|v|q|g] x 64
#define PROJ_TSTRIDE (BATCH * NFIELD)    // 4096 floats per t
static constexpr float EPS = 1e-6f;

#define AS1 __attribute__((address_space(1)))
#define AS3 __attribute__((address_space(3)))

// ============================ projection GEMM v2 ============================
// BM=128, BN=256, BK=16, 256 threads, 8Mx16N per thread.
// LDS bytes per k-step: 2xb128 (As) + 4xb128 (Bs) = 96B / 256 FLOP
//   -> 96 B/cyc/CU at full FMA rate < 128 B/cyc LDS peak -> VALU-bound.

#define BM   128
#define BK   16
#define APAD 128
#define BPAD 260

__global__ __launch_bounds__(256, 2) void proj_kernel(
    const float* __restrict__ x,
    const float* __restrict__ Wk, const float* __restrict__ Wv,
    const float* __restrict__ Wq, const float* __restrict__ Wb,
    const float* __restrict__ bb,
    float* __restrict__ proj)
{
    __shared__ float As[BK][APAD];   //  8 KB
    __shared__ float Bs[BK][BPAD];   // 16.6 KB

    const int tid = threadIdx.x;
    const int tx = tid & 15, ty = tid >> 4;
    const int ms  = tid & 127;        // staging row (0..127)
    const int jj0 = tid >> 7;         // staging k-quad base (0 or 1; +2 for 2nd)
    const size_t mbase = (size_t)blockIdx.x * BM;
    const float* xrow = x + (mbase + ms) * DIM;
    const int nf = tid >> 6, n63 = tid & 63;
    const float* Wrow = (nf == 0 ? Wk : nf == 1 ? Wv : nf == 2 ? Wq : Wb)
                        + (size_t)n63 * DIM;

    float acc[8][16] = {};            // [mm][w*4+e]

    // prefetch k-chunk 0
    float4 xa0 = *(const float4*)(xrow + 4 * jj0);
    float4 xa1 = *(const float4*)(xrow + 4 * (jj0 + 2));
    float4 w0 = *(const float4*)(Wrow + 0);
    float4 w1 = *(const float4*)(Wrow + 4);
    float4 w2 = *(const float4*)(Wrow + 8);
    float4 w3 = *(const float4*)(Wrow + 12);

    for (int k0 = 0; k0 < DIM; k0 += BK) {
        __syncthreads();
        As[4 * jj0 + 0][ms] = xa0.x;
        As[4 * jj0 + 1][ms] = xa0.y;
        As[4 * jj0 + 2][ms] = xa0.z;
        As[4 * jj0 + 3][ms] = xa0.w;
        As[4 * jj0 + 8][ms] = xa1.x;
        As[4 * jj0 + 9][ms] = xa1.y;
        As[4 * jj0 +10][ms] = xa1.z;
        As[4 * jj0 +11][ms] = xa1.w;
        Bs[ 0][tid] = w0.x; Bs[ 1][tid] = w0.y; Bs[ 2][tid] = w0.z; Bs[ 3][tid] = w0.w;
        Bs[ 4][tid] = w1.x; Bs[ 5][tid] = w1.y; Bs[ 6][tid] = w1.z; Bs[ 7][tid] = w1.w;
        Bs[ 8][tid] = w2.x; Bs[ 9][tid] = w2.y; Bs[10][tid] = w2.z; Bs[11][tid] = w2.w;
        Bs[12][tid] = w3.x; Bs[13][tid] = w3.y; Bs[14][tid] = w3.z; Bs[15][tid] = w3.w;
        __syncthreads();

        if (k0 + BK < DIM) {          // prefetch next chunk (hidden under compute)
            const int kn = k0 + BK;
            xa0 = *(const float4*)(xrow + kn + 4 * jj0);
            xa1 = *(const float4*)(xrow + kn + 4 * (jj0 + 2));
            w0 = *(const float4*)(Wrow + kn + 0);
            w1 = *(const float4*)(Wrow + kn + 4);
            w2 = *(const float4*)(Wrow + kn + 8);
            w3 = *(const float4*)(Wrow + kn + 12);
        }

        #pragma unroll
        for (int k = 0; k < BK; ++k) {
            float a[8];
            { float4 t = *(const float4*)(&As[k][ty * 8]);
              a[0] = t.x; a[1] = t.y; a[2] = t.z; a[3] = t.w; }
            { float4 t = *(const float4*)(&As[k][ty * 8 + 4]);
              a[4] = t.x; a[5] = t.y; a[6] = t.z; a[7] = t.w; }
            float bfr[16];
            #pragma unroll
            for (int w = 0; w < 4; ++w) {
                float4 t = *(const float4*)(&Bs[k][64 * w + 4 * tx]);
                bfr[4 * w + 0] = t.x; bfr[4 * w + 1] = t.y;
                bfr[4 * w + 2] = t.z; bfr[4 * w + 3] = t.w;
            }
            #pragma unroll
            for (int mm = 0; mm < 8; ++mm)
                #pragma unroll
                for (int nn = 0; nn < 16; ++nn)
                    acc[mm][nn] = fmaf(a[mm], bfr[nn], acc[mm][nn]);
        }
    }

    // epilogue: k-norm (cols 0..3 = k field) and sigmoid gate (cols 12..15)
    #pragma unroll
    for (int mm = 0; mm < 8; ++mm) {
        float s = acc[mm][0] * acc[mm][0] + acc[mm][1] * acc[mm][1]
                + acc[mm][2] * acc[mm][2] + acc[mm][3] * acc[mm][3];
        s += __shfl_xor(s, 1); s += __shfl_xor(s, 2);
        s += __shfl_xor(s, 4); s += __shfl_xor(s, 8);
        const float sc = 1.f / (sqrtf(s) + EPS);
        acc[mm][0] *= sc; acc[mm][1] *= sc; acc[mm][2] *= sc; acc[mm][3] *= sc;
    }
    const float bb0 = bb[4 * tx + 0], bb1 = bb[4 * tx + 1];
    const float bb2 = bb[4 * tx + 2], bb3 = bb[4 * tx + 3];
    #pragma unroll
    for (int mm = 0; mm < 8; ++mm) {
        acc[mm][12] = 1.f / (1.f + __expf(-(acc[mm][12] + bb0)));
        acc[mm][13] = 1.f / (1.f + __expf(-(acc[mm][13] + bb1)));
        acc[mm][14] = 1.f / (1.f + __expf(-(acc[mm][14] + bb2)));
        acc[mm][15] = 1.f / (1.f + __expf(-(acc[mm][15] + bb3)));
    }
    #pragma unroll
    for (int mm = 0; mm < 8; ++mm) {
        float* dst = proj + (mbase + ty * 8 + mm) * NFIELD;
        *(float4*)(dst +   0 + 4 * tx) = make_float4(acc[mm][ 0], acc[mm][ 1], acc[mm][ 2], acc[mm][ 3]);
        *(float4*)(dst +  64 + 4 * tx) = make_float4(acc[mm][ 4], acc[mm][ 5], acc[mm][ 6], acc[mm][ 7]);
        *(float4*)(dst + 128 + 4 * tx) = make_float4(acc[mm][ 8], acc[mm][ 9], acc[mm][10], acc[mm][11]);
        *(float4*)(dst + 192 + 4 * tx) = make_float4(acc[mm][12], acc[mm][13], acc[mm][14], acc[mm][15]);
    }
}

// ============================ sequential scan v6 ============================
// One 1024-thread block per batch: 16 waves x 4 rows = 64 rows. 4 waves/SIMD
// so one wave's stall cycles are absorbed by the other three (R5 had exactly
// 1 wave per busy SIMD -> nothing to overlap the ~150 cyc/step residual).
// Staging via 16B global_load_lds (2 insts/wave/chunk); silu fused at store.

template <int CTRL>
__device__ __forceinline__ float dpp_add(float x) {
    int yi = __builtin_amdgcn_update_dpp(0, __float_as_int(x), CTRL, 0xF, 0xF, true);
    return x + __int_as_float(yi);
}
__device__ __forceinline__ float reduce16(float x) {
    x = dpp_add<0x121>(x);   // row_ror:1
    x = dpp_add<0x122>(x);   // row_ror:2
    x = dpp_add<0x124>(x);   // row_ror:4
    x = dpp_add<0x128>(x);   // row_ror:8
    return x;
}
__device__ __forceinline__ float dot4r(const float4& u, const float4& w) {
    float t0 = u.x * w.x; t0 = fmaf(u.y, w.y, t0);
    float t1 = u.z * w.z; t1 = fmaf(u.w, w.w, t1);
    return reduce16(t0 + t1);
}

#define CH 32
#define NCHUNK (T_STEPS / CH)

__global__ __launch_bounds__(1024) void scan_kernel(
    const float* __restrict__ proj,  // [T][B][256]
    const float* __restrict__ S0,    // [B][64][64]
    float* __restrict__ out,         // [T][B][64]
    float* __restrict__ Sfin)        // [B][64][64]
{
    __shared__ float KQ[2][CH][128];   // [s][0:64)=kn, [64:128)=q  (32 KB)
    __shared__ float VP[2][CH][64];    // v plane                   (16 KB)
    __shared__ float GP[2][CH][64];    // g plane                   (16 KB)

    const int tid = threadIdx.x;          // 0..1023
    const int w   = tid >> 6;             // wave 0..15
    const int wl  = tid & 63;
    const int gg  = wl >> 4;              // row-group within wave (0..3)
    const int l   = wl & 15;
    const int b   = blockIdx.x;           // batch
    const int i   = w * 4 + gg;           // row 0..63
    const int c0  = l * 4;

    const size_t srow = ((size_t)(b * 64 + i)) * 64 + c0;
    float4 S = *(const float4*)(S0 + srow);

    const float* pb = proj + (size_t)b * NFIELD;

    // --- DMA maps (16B per lane, wave-uniform LDS base) ---
    // KQ: wave w stages 1024B at KQ+w*1024: s = 2w + (wl>>5),
    //     field = (wl&31)*4, shifted +64 into q when (wl&31)>=16.
    const int l31  = wl & 31;
    const int kq_f = l31 * 4 + ((l31 >= 16) ? 64 : 0);
    const int kq_s = wl >> 5;
    // V (waves 0..7) / G (waves 8..15): wave w8 stages 1024B = 4 steps:
    //     s = 4*w8 + (wl>>4), field = {64|192} + (wl&15)*4.
    const int w8   = w & 7;
    const int vg_s = wl >> 4;
    const int vg_f = ((w < 8) ? 64 : 192) + (wl & 15) * 4;

    auto stage = [&](int c, int nb) {
        const float* cbase = pb + (size_t)c * CH * PROJ_TSTRIDE;
        {
            const float* g = cbase + (size_t)(2 * w + kq_s) * PROJ_TSTRIDE + kq_f;
            void* lp = (char*)&KQ[nb][0][0] + w * 1024;
            __builtin_amdgcn_global_load_lds((const AS1 void*)g, (AS3 void*)lp, 16, 0, 0);
        }
        {
            const float* g = cbase + (size_t)(4 * w8 + vg_s) * PROJ_TSTRIDE + vg_f;
            void* lp = (char*)((w < 8) ? &VP[nb][0][0] : &GP[nb][0][0]) + w8 * 1024;
            __builtin_amdgcn_global_load_lds((const AS1 void*)g, (AS3 void*)lp, 16, 0, 0);
        }
    };

    float4 kn_s[4], q_s[4];
    float  v_s[4], g_s[4];
    auto ldslot = [&](int cb, int s, int j) {
        kn_s[j] = *(const float4*)(&KQ[cb][s][c0]);
        q_s[j]  = *(const float4*)(&KQ[cb][s][64 + c0]);
        v_s[j]  = VP[cb][s][i];
        g_s[j]  = GP[cb][s][i];
    };

    stage(0, 0);
    __syncthreads();

    float a;
    auto prime = [&](int nb) {
        #pragma unroll
        for (int j = 0; j < 4; ++j) ldslot(nb, j, j);
        a = dot4r(S, kn_s[0]);           // recompute carried dot from S
    };
    prime(0);

    float osel = 0.f;

    for (int c = 0; c < NCHUNK; ++c) {
        const int cb = c & 1;
        const bool more = (c + 1 < NCHUNK);
        if (more) stage(c + 1, cb ^ 1);  // DMA in flight across this chunk

        #pragma unroll
        for (int s = 0; s < CH; ++s) {
            const int j = s & 3;
            const float4 kn = kn_s[j], q = q_s[j];
            const float  v = v_s[j], g = g_s[j];

            if (s + 4 < CH) ldslot(cb, s + 4, j);   // refill freed slot

            const float d = v - a;
            S.x = fmaf(d, kn.x, g * S.x);
            S.y = fmaf(d, kn.y, g * S.y);
            S.z = fmaf(d, kn.z, g * S.z);
            S.w = fmaf(d, kn.w, g * S.w);

            const float sq = dot4r(S, q);
            if (s + 1 < CH) a = dot4r(S, kn_s[(s + 1) & 3]);

            osel = ((s & 15) == l) ? sq : osel;
            if ((s & 15) == 15) {
                const float sig = 1.f / (1.f + __expf(-osel));
                const int tbase = c * CH + (s - 15);
                out[((size_t)(tbase + l) * BATCH + b) * 64 + i] = osel * osel * sig;
            }
        }

        if (more) {
            __syncthreads();             // next chunk's DMA complete
            prime(cb ^ 1);
        }
    }

    *(float4*)(Sfin + srow) = S;
}

// ================================ launch ================================
extern "C" void kernel_launch(void* const* d_in, const int* in_sizes, int n_in,
                              void* d_out, int out_size, void* d_ws, size_t ws_size,
                              hipStream_t stream) {
    const float* x  = (const float*)d_in[0];
    const float* S0 = (const float*)d_in[1];
    const float* Wk = (const float*)d_in[2];
    const float* Wv = (const float*)d_in[3];
    const float* Wq = (const float*)d_in[4];
    const float* Wb = (const float*)d_in[5];
    const float* bb = (const float*)d_in[6];

    float* out  = (float*)d_out;                               // [T][B][64]
    float* Sfin = out + (size_t)T_STEPS * BATCH * NSTATE;      // [B][64][64]
    float* proj = (float*)d_ws;                                // [T*B][256] = 33.5 MB

    proj_kernel<<<(T_STEPS * BATCH) / BM, 256, 0, stream>>>(x, Wk, Wv, Wq, Wb, bb, proj);
    scan_kernel<<<BATCH, 1024, 0, stream>>>(proj, S0, out, Sfin);
}